// Round 6
// baseline (842.013 us; speedup 1.0000x reference)
//
#include <hip/hip_runtime.h>
#include <math.h>

#define IMG 768
#define TX 48
#define TY 24
#define KF 4
#define ITX (TX + 2 * KF)   // 56
#define ITY (TY + 2 * KF)   // 32
#define NBX (IMG / TX)      // 16
#define NBY (IMG / TY)      // 32 -> 512 blocks = exactly 2 per CU
#define NT 512
#define RES_SCALE 0.1f
#define NITER 64

// Exact GELU: 0.5*x*(1+erf(x/sqrt(2))), erf via Abramowitz-Stegun 7.1.26
// (|abs err| < 1.5e-7), restructured to 10 VALU + 2 trans:
//   erf(|x|/sqrt2) = 1 - P(k)*exp2(-x^2*log2e/2),  k = rcp(1 + p'*|x|)
//   gelu(x) = 0.5x + 0.5|x| * erf(|x|/sqrt2)          (sign folded via |.|)
__device__ __forceinline__ float gelu_exact(float x) {
    float u = x * x;
    float e = __builtin_amdgcn_exp2f(u * -0.72134752044448f);      // exp(-x^2/2)
    float kk = __builtin_amdgcn_rcpf(fmaf(0.23164188662f, fabsf(x), 1.0f));
    float p = fmaf(1.061405429f, kk, -1.453152027f);
    p = fmaf(p, kk, 1.421413741f);
    p = fmaf(p, kk, -0.284496736f);
    p = fmaf(p, kk, 0.254829592f);
    p *= kk;
    float r = fmaf(-e, p, 1.0f);      // erf(|x|/sqrt2) in [0,1]
    float hx = 0.5f * x;
    return fmaf(fabsf(hx), r, hx);    // abs is a free VOP3 modifier
}

// F.interpolate(bilinear, align_corners=False) from the 8x8 seed,
// half-pixel centers; edge handling == index clamp.
__device__ __forceinline__ float bilinear8(const float* __restrict__ seed,
                                           int gy, int gx) {
    float sy = fmaf((float)gy, 0.0104166667f, -0.4947916667f);  // (gy+.5)/96-.5
    float sx = fmaf((float)gx, 0.0104166667f, -0.4947916667f);
    float fy = floorf(sy), fx = floorf(sx);
    float wy = sy - fy, wx = sx - fx;
    int y0 = (int)fy, x0 = (int)fx;
    int y0c = min(max(y0, 0), 7), y1c = min(max(y0 + 1, 0), 7);
    int x0c = min(max(x0, 0), 7), x1c = min(max(x0 + 1, 0), 7);
    float v00 = seed[y0c * 8 + x0c], v01 = seed[y0c * 8 + x1c];
    float v10 = seed[y1c * 8 + x0c], v11 = seed[y1c * 8 + x1c];
    float top = v00 + wx * (v01 - v00);
    float bot = v10 + wx * (v11 - v10);
    return top + wy * (bot - top);
}

// KF residual iterations fused per launch; shrinking-halo LDS tiles.
// Channel-outer over a batch of B pixels per thread (B independent 9-FMA
// chains = ILP), branchless exact GELU, raw-w2 accumulate with the 0.1
// residual scale folded into the single store fma. FIRST launch stages the
// bilinear upsample of the seed directly into LDS (no separate resize pass).
template <bool FIRST>
__global__ __launch_bounds__(NT, 4) void fused_steps(
        const float* __restrict__ seed,
        const float* __restrict__ xin, float* __restrict__ xout,
        const float* __restrict__ gw1, const float* __restrict__ gb1,
        const float* __restrict__ gw2, const float* __restrict__ gb2) {
    __shared__ float buf[2][ITY * ITX];   // 2 x 32x56 x 4B = 14.3 KB
    const int tid = threadIdx.x;
    const int bx = blockIdx.x % NBX, by = blockIdx.x / NBX;
    const int gx0 = bx * TX - KF, gy0 = by * TY - KF;
    const bool border = (bx == 0) | (bx == NBX - 1) | (by == 0) | (by == NBY - 1);

    // ---- stage 56x32 input tile (zeros outside image = 'SAME' zero pad) ----
    if (FIRST) {
        for (int t = tid; t < ITY * ITX; t += NT) {
            int r = t / ITX, c = t - r * ITX;
            int gy = gy0 + r, gx = gx0 + c;
            float v = 0.0f;
            if (gy >= 0 && gy < IMG && gx >= 0 && gx < IMG)
                v = bilinear8(seed, gy, gx);
            buf[0][t] = v;
        }
    } else if (!border) {
        int t = tid;                       // 14*32 = 448 float4 <= 512 threads
        if (t < (ITX / 4) * ITY) {
            int r = t / (ITX / 4), c4 = t - r * (ITX / 4);
            *reinterpret_cast<float4*>(&buf[0][r * ITX + c4 * 4]) =
                *reinterpret_cast<const float4*>(&xin[(gy0 + r) * IMG + gx0 + c4 * 4]);
        }
    } else {
        for (int t = tid; t < ITY * ITX; t += NT) {
            int r = t / ITX, c = t - r * ITX;
            int gy = gy0 + r, gx = gx0 + c;
            float v = 0.0f;
            if (gy >= 0 && gy < IMG && gx >= 0 && gx < IMG) v = xin[gy * IMG + gx];
            buf[0][t] = v;
        }
    }
    __syncthreads();

    const float b2v = gb2[0];

#pragma unroll
    for (int j = 0; j < KF; ++j) {
        const int SX = ITX - 2 - 2 * j;    // 54,52,50,48
        const int SY = ITY - 2 - 2 * j;    // 30,28,26,24
        const int off = j + 1;
        const int total = SX * SY;         // 1620,1456,1300,1152
        const int B = (total + NT - 1) / NT;  // 4,3,3,3 (compile-time)
        const float* __restrict__ src = &buf[j & 1][0];
        float* __restrict__ dst = &buf[(j & 1) ^ 1][0];

        int rr[4], cc[4];
        bool ok[4];
        float nb[4][9];
#pragma unroll
        for (int k = 0; k < B; ++k) {
            int p = tid + k * NT;
            ok[k] = p < total;
            if (!ok[k]) p = total - 1;     // clamp: duplicate of a valid pixel
            int q = p / SX;                // SX compile-time -> magic mul
            rr[k] = off + q;
            cc[k] = off + (p - q * SX);
            const float* s0 = &src[(rr[k] - 1) * ITX + cc[k] - 1];
            nb[k][0] = s0[0];           nb[k][1] = s0[1];           nb[k][2] = s0[2];
            nb[k][3] = s0[ITX];         nb[k][4] = s0[ITX + 1];     nb[k][5] = s0[ITX + 2];
            nb[k][6] = s0[2 * ITX];     nb[k][7] = s0[2 * ITX + 1]; nb[k][8] = s0[2 * ITX + 2];
        }
        float y[4];
#pragma unroll
        for (int k = 0; k < B; ++k) y[k] = b2v;

#pragma unroll
        for (int ch = 0; ch < 16; ++ch) {
            const float* wc = &gw1[ch * 9];   // uniform -> s_load
            const float b1c = gb1[ch];
            const float w2c = gw2[ch];        // raw; 0.1 folded into store
#pragma unroll
            for (int k = 0; k < B; ++k) {     // B independent 9-FMA chains
                float t = b1c;
                t = fmaf(wc[0], nb[k][0], t);
                t = fmaf(wc[1], nb[k][1], t);
                t = fmaf(wc[2], nb[k][2], t);
                t = fmaf(wc[3], nb[k][3], t);
                t = fmaf(wc[4], nb[k][4], t);
                t = fmaf(wc[5], nb[k][5], t);
                t = fmaf(wc[6], nb[k][6], t);
                t = fmaf(wc[7], nb[k][7], t);
                t = fmaf(wc[8], nb[k][8], t);
                y[k] = fmaf(w2c, gelu_exact(t), y[k]);
            }
        }

#pragma unroll
        for (int k = 0; k < B; ++k) {
            float v = fmaf(RES_SCALE, y[k], nb[k][4]);
            if (border) {
                int gy = gy0 + rr[k], gx = gx0 + cc[k];
                bool inimg = (gy >= 0) & (gy < IMG) & (gx >= 0) & (gx < IMG);
                // ghost pixels outside image stay 0 every iteration (zero pad)
                if (!inimg) v = 0.0f;
            }
            if (ok[k]) dst[rr[k] * ITX + cc[k]] = v;
        }
        __syncthreads();
    }

    // ---- drain inner 48x24 (always fully in-image; KF even -> buf[0]) ----
    for (int t = tid; t < (TX / 4) * TY; t += NT) {   // 12*24 = 288 float4
        int r = t / (TX / 4), c4 = t - r * (TX / 4);
        *reinterpret_cast<float4*>(&xout[(gy0 + KF + r) * IMG + gx0 + KF + c4 * 4]) =
            *reinterpret_cast<const float4*>(&buf[0][(KF + r) * ITX + KF + c4 * 4]);
    }
}

extern "C" void kernel_launch(void* const* d_in, const int* in_sizes, int n_in,
                              void* d_out, int out_size, void* d_ws, size_t ws_size,
                              hipStream_t stream) {
    const float* seed = (const float*)d_in[0];
    const float* w1   = (const float*)d_in[1];
    const float* b1   = (const float*)d_in[2];
    const float* w2   = (const float*)d_in[3];
    const float* b2   = (const float*)d_in[4];
    // d_in[5]/d_in[6] are rows/cols = 768/768 (fixed by setup_inputs)

    float* out = (float*)d_out;
    float* ws  = (float*)d_ws;   // second ping-pong buffer (2.36 MB)

    float* a = out;
    float* b = ws;
    // 16 launches; first fuses the bilinear resize; even count -> ends in d_out
    fused_steps<true><<<NBX * NBY, NT, 0, stream>>>(seed, a, b, w1, b1, w2, b2);
    { float* t = a; a = b; b = t; }
    for (int it = KF; it < NITER; it += KF) {
        fused_steps<false><<<NBX * NBY, NT, 0, stream>>>(seed, a, b, w1, b1, w2, b2);
        float* t = a; a = b; b = t;
    }
}

// Round 7
// 630.689 us; speedup vs baseline: 1.3351x; 1.3351x over previous
//
#include <hip/hip_runtime.h>
#include <math.h>

#define IMG 768
#define TX 48
#define TY 24
#define KF 4
#define ITX (TX + 2 * KF)   // 56
#define ITY (TY + 2 * KF)   // 32
#define NBX (IMG / TX)      // 16
#define NBY (IMG / TY)      // 32 -> 512 blocks = exactly 2 per CU
#define NT 448              // 7 waves; staging = exactly 1 float4/thread
#define RES_SCALE 0.1f
#define NITER 64

// Exact GELU: 0.5*x*(1+erf(x/sqrt(2))), erf via Abramowitz-Stegun 7.1.26
// (|abs err| < 1.5e-7), restructured to 10 VALU + 2 trans:
//   erf(|x|/sqrt2) = 1 - P(k)*exp2(-x^2*log2e/2),  k = rcp(1 + p'*|x|)
//   gelu(x) = 0.5x + |0.5x| * erf(|x|/sqrt2)          (sign folded via |.|)
__device__ __forceinline__ float gelu_exact(float x) {
    float u = x * x;
    float e = __builtin_amdgcn_exp2f(u * -0.72134752044448f);      // exp(-x^2/2)
    float kk = __builtin_amdgcn_rcpf(fmaf(0.23164188662f, fabsf(x), 1.0f));
    float p = fmaf(1.061405429f, kk, -1.453152027f);
    p = fmaf(p, kk, 1.421413741f);
    p = fmaf(p, kk, -0.284496736f);
    p = fmaf(p, kk, 0.254829592f);
    p *= kk;
    float r = fmaf(-e, p, 1.0f);      // erf(|x|/sqrt2) in [0,1]
    float hx = 0.5f * x;
    return fmaf(fabsf(hx), r, hx);    // abs is a free VOP3 modifier
}

// F.interpolate(bilinear, align_corners=False) from the 8x8 seed,
// half-pixel centers; edge handling == index clamp.
__device__ __forceinline__ float bilinear8(const float* __restrict__ seed,
                                           int gy, int gx) {
    float sy = fmaf((float)gy, 0.0104166667f, -0.4947916667f);  // (gy+.5)/96-.5
    float sx = fmaf((float)gx, 0.0104166667f, -0.4947916667f);
    float fy = floorf(sy), fx = floorf(sx);
    float wy = sy - fy, wx = sx - fx;
    int y0 = (int)fy, x0 = (int)fx;
    int y0c = min(max(y0, 0), 7), y1c = min(max(y0 + 1, 0), 7);
    int x0c = min(max(x0, 0), 7), x1c = min(max(x0 + 1, 0), 7);
    float v00 = seed[y0c * 8 + x0c], v01 = seed[y0c * 8 + x1c];
    float v10 = seed[y1c * 8 + x0c], v11 = seed[y1c * 8 + x1c];
    float top = v00 + wx * (v01 - v00);
    float bot = v10 + wx * (v11 - v10);
    return top + wy * (bot - top);
}

// KF residual iterations fused per launch; shrinking-halo LDS tiles.
// Channel-outer over a batch of B pixels per thread. The asm fence between
// the conv phase and the activation phase pins all B conv accumulators live
// (two-phase codegen, ILP=B) without the cost of R3's mn/branch — prevents
// the compiler's k-outer interchange that serialized R6 (VGPR 36 fiasco).
template <bool FIRST>
__global__ __launch_bounds__(NT, 2) void fused_steps(
        const float* __restrict__ seed,
        const float* __restrict__ xin, float* __restrict__ xout,
        const float* __restrict__ gw1, const float* __restrict__ gb1,
        const float* __restrict__ gw2, const float* __restrict__ gb2) {
    __shared__ float buf[2][ITY * ITX];   // 2 x 32x56 x 4B = 14.3 KB
    const int tid = threadIdx.x;
    const int bx = blockIdx.x % NBX, by = blockIdx.x / NBX;
    const int gx0 = bx * TX - KF, gy0 = by * TY - KF;
    const bool border = (bx == 0) | (bx == NBX - 1) | (by == 0) | (by == NBY - 1);

    // ---- stage 56x32 input tile (zeros outside image = 'SAME' zero pad) ----
    if (FIRST) {
        for (int t = tid; t < ITY * ITX; t += NT) {
            int r = t / ITX, c = t - r * ITX;
            int gy = gy0 + r, gx = gx0 + c;
            float v = 0.0f;
            if (gy >= 0 && gy < IMG && gx >= 0 && gx < IMG)
                v = bilinear8(seed, gy, gx);
            buf[0][t] = v;
        }
    } else if (!border) {
        // exactly one float4 per thread: 14*32 = 448
        int r = tid / (ITX / 4), c4 = tid - r * (ITX / 4);
        *reinterpret_cast<float4*>(&buf[0][r * ITX + c4 * 4]) =
            *reinterpret_cast<const float4*>(&xin[(gy0 + r) * IMG + gx0 + c4 * 4]);
    } else {
        for (int t = tid; t < ITY * ITX; t += NT) {   // 4 iters exact
            int r = t / ITX, c = t - r * ITX;
            int gy = gy0 + r, gx = gx0 + c;
            float v = 0.0f;
            if (gy >= 0 && gy < IMG && gx >= 0 && gx < IMG) v = xin[gy * IMG + gx];
            buf[0][t] = v;
        }
    }
    __syncthreads();

    const float b2v = gb2[0];

#pragma unroll
    for (int j = 0; j < KF; ++j) {
        const int SX = ITX - 2 - 2 * j;    // 54,52,50,48
        const int SY = ITY - 2 - 2 * j;    // 30,28,26,24
        const int off = j + 1;
        const int total = SX * SY;         // 1620,1456,1300,1152
        const int B = (total + NT - 1) / NT;  // 4,4,3,3 (compile-time)
        const float* __restrict__ src = &buf[j & 1][0];
        float* __restrict__ dst = &buf[(j & 1) ^ 1][0];

        int rr[4], cc[4];
        bool ok[4];
        float nb[4][9];
#pragma unroll
        for (int k = 0; k < B; ++k) {
            int p = tid + k * NT;
            ok[k] = p < total;
            if (!ok[k]) p = total - 1;     // clamp: duplicate of a valid pixel
            int q = p / SX;                // SX compile-time -> magic mul
            rr[k] = off + q;
            cc[k] = off + (p - q * SX);
            const float* s0 = &src[(rr[k] - 1) * ITX + cc[k] - 1];
            nb[k][0] = s0[0];           nb[k][1] = s0[1];           nb[k][2] = s0[2];
            nb[k][3] = s0[ITX];         nb[k][4] = s0[ITX + 1];     nb[k][5] = s0[ITX + 2];
            nb[k][6] = s0[2 * ITX];     nb[k][7] = s0[2 * ITX + 1]; nb[k][8] = s0[2 * ITX + 2];
        }
        float y[4];
#pragma unroll
        for (int k = 0; k < B; ++k) y[k] = b2v;

#pragma unroll
        for (int ch = 0; ch < 16; ++ch) {
            const float* wc = &gw1[ch * 9];   // uniform -> s_load
            const float b1c = gb1[ch];
            const float w2c = gw2[ch];        // raw; 0.1 folded into store
            float a[4];
#pragma unroll
            for (int k = 0; k < B; ++k) {     // B independent 9-FMA chains
                float t = b1c;
                t = fmaf(wc[0], nb[k][0], t);
                t = fmaf(wc[1], nb[k][1], t);
                t = fmaf(wc[2], nb[k][2], t);
                t = fmaf(wc[3], nb[k][3], t);
                t = fmaf(wc[4], nb[k][4], t);
                t = fmaf(wc[5], nb[k][5], t);
                t = fmaf(wc[6], nb[k][6], t);
                t = fmaf(wc[7], nb[k][7], t);
                t = fmaf(wc[8], nb[k][8], t);
                a[k] = t;
            }
            // zero-cost fence: all B conv results live before activation ->
            // two-phase schedule, no loop interchange, nb[] stays hoisted
            if (B == 4)
                asm volatile("" : "+v"(a[0]), "+v"(a[1]), "+v"(a[2]), "+v"(a[3]));
            else
                asm volatile("" : "+v"(a[0]), "+v"(a[1]), "+v"(a[2]));
#pragma unroll
            for (int k = 0; k < B; ++k)
                y[k] = fmaf(w2c, gelu_exact(a[k]), y[k]);
        }

#pragma unroll
        for (int k = 0; k < B; ++k) {
            float v = fmaf(RES_SCALE, y[k], nb[k][4]);
            if (border) {
                int gy = gy0 + rr[k], gx = gx0 + cc[k];
                bool inimg = (gy >= 0) & (gy < IMG) & (gx >= 0) & (gx < IMG);
                // ghost pixels outside image stay 0 every iteration (zero pad)
                if (!inimg) v = 0.0f;
            }
            if (ok[k]) dst[rr[k] * ITX + cc[k]] = v;
        }
        __syncthreads();
    }

    // ---- drain inner 48x24 (always fully in-image; KF even -> buf[0]) ----
    {
        int t = tid;                      // 12*24 = 288 float4 <= 448 threads
        if (t < (TX / 4) * TY) {
            int r = t / (TX / 4), c4 = t - r * (TX / 4);
            *reinterpret_cast<float4*>(&xout[(gy0 + KF + r) * IMG + gx0 + KF + c4 * 4]) =
                *reinterpret_cast<const float4*>(&buf[0][(KF + r) * ITX + KF + c4 * 4]);
        }
    }
}

extern "C" void kernel_launch(void* const* d_in, const int* in_sizes, int n_in,
                              void* d_out, int out_size, void* d_ws, size_t ws_size,
                              hipStream_t stream) {
    const float* seed = (const float*)d_in[0];
    const float* w1   = (const float*)d_in[1];
    const float* b1   = (const float*)d_in[2];
    const float* w2   = (const float*)d_in[3];
    const float* b2   = (const float*)d_in[4];
    // d_in[5]/d_in[6] are rows/cols = 768/768 (fixed by setup_inputs)

    float* out = (float*)d_out;
    float* ws  = (float*)d_ws;   // second ping-pong buffer (2.36 MB)

    float* a = out;
    float* b = ws;
    // 16 launches; first fuses the bilinear resize; even count -> ends in d_out
    fused_steps<true><<<NBX * NBY, NT, 0, stream>>>(seed, a, b, w1, b1, w2, b2);
    { float* t = a; a = b; b = t; }
    for (int it = KF; it < NITER; it += KF) {
        fused_steps<false><<<NBX * NBY, NT, 0, stream>>>(seed, a, b, w1, b1, w2, b2);
        float* t = a; a = b; b = t;
    }
}